// Round 17
// baseline (302.476 us; speedup 1.0000x reference)
//
#include <hip/hip_runtime.h>
#include <hip/hip_bf16.h>
#include <hip/hip_fp16.h>

#define N_NODES   100000
#define N_EDGES   1600000
#define N_GRAPHS  1024
#define EMB       32
#define HID       64
#define N_CLASSES 10
#define SCAN_BLOCKS 391   // ceil(100000/256)
#define NCOMBO 153        // 17 shape ids x 9 color ids
#define BUCK_NODES 448    // nodes per dst-bucket
#define NBUCK 224         // ceil(100000/448)
#define BIN_CAP 8192      // per-bucket staging capacity (mean 7143, +12 sigma)
#define EPB 4096          // edges per binA block

// ---------------- prep: combo[v], per-graph counts ----------------
__global__ __launch_bounds__(256) void prep_kernel(
    const int* __restrict__ sid, const int* __restrict__ cid,
    const int* __restrict__ batch, int* __restrict__ combo, int* __restrict__ cnt) {
    int v = blockIdx.x * 256 + threadIdx.x;
    if (v < N_NODES) {
        combo[v] = sid[v] * 9 + cid[v];
        atomicAdd(&cnt[batch[v]], 1);
    }
}

// ---------------- combined table (fp16): TCh[s*9+c][j] = (st[s]@W1)[j] + (ct[c]@W1)[j] ----------------
__global__ __launch_bounds__(64) void tc_kernel(
    const float* __restrict__ st, const float* __restrict__ ct,
    const float* __restrict__ W1, __half* __restrict__ TCh) {
    int r = blockIdx.x, j = threadIdx.x;
    int s = r / 9, c = r % 9;
    float acc = 0.0f;
    if (s != 0) {
#pragma unroll
        for (int k = 0; k < EMB; ++k) acc = fmaf(st[s * EMB + k], W1[k * HID + j], acc);
    }
    if (c != 0) {
#pragma unroll
        for (int k = 0; k < EMB; ++k) acc = fmaf(ct[c * EMB + k], W1[k * HID + j], acc);
    }
    TCh[r * HID + j] = __float2half_rn(acc);
}

// ---------------- binA: block-local counting sort by dst-bucket, chunked flush ----------------
__global__ __launch_bounds__(512) void binA_kernel(
    const int* __restrict__ src, const int* __restrict__ dst,
    const int* __restrict__ combo, int* __restrict__ gcur,
    int2* __restrict__ gbin) {
    __shared__ int2 stg[EPB];            // 32 KB
    __shared__ int hist[NBUCK];
    __shared__ int base[NBUCK + 1];
    __shared__ int gstart[NBUCK];
    __shared__ int scanbuf[256];
    int t = threadIdx.x;
    int e0 = blockIdx.x * EPB;
    for (int i = t; i < NBUCK; i += 512) hist[i] = 0;
    __syncthreads();

    int2 myq[8];
    int mybo[8];
#pragma unroll
    for (int i = 0; i < 8; ++i) {
        int e = e0 + t + i * 512;
        if (e < N_EDGES) {
            int d = dst[e];
            int s = src[e];
            unsigned b = (unsigned)d / BUCK_NODES;
            int off = atomicAdd(&hist[b], 1);
            myq[i].x = s | (combo[s] << 17);
            myq[i].y = d;
            mybo[i] = (int)(b << 16) | off;
        } else {
            mybo[i] = -1;
        }
    }
    __syncthreads();

    int h = (t < NBUCK) ? hist[t] : 0;
    if (t < 256) scanbuf[t] = h;
    __syncthreads();
#pragma unroll
    for (int off = 1; off < 256; off <<= 1) {
        int x = (t < 256 && t >= off) ? scanbuf[t - off] : 0;
        __syncthreads();
        if (t < 256) scanbuf[t] += x;
        __syncthreads();
    }
    if (t < NBUCK) base[t] = scanbuf[t] - h;
    if (t == 0) base[NBUCK] = scanbuf[255];
    __syncthreads();
#pragma unroll
    for (int i = 0; i < 8; ++i) {
        if (mybo[i] >= 0) {
            int b = mybo[i] >> 16, off = mybo[i] & 0xFFFF;
            stg[base[b] + off] = myq[i];
        }
    }
    if (t < NBUCK) {
        int n = hist[t];
        gstart[t] = n ? atomicAdd(&gcur[t], n) : 0;
    }
    __syncthreads();
    int total = base[NBUCK];
    for (int i = t; i < total; i += 512) {
        int2 q = stg[i];
        unsigned b = (unsigned)q.y / BUCK_NODES;
        gbin[(size_t)b * BIN_CAP + gstart[b] + (i - base[b])] = q;
    }
}

// ---------------- bscan: exclusive scan of gcur[224] -> bktbase ----------------
__global__ __launch_bounds__(256) void bscan_kernel(const int* __restrict__ gcur,
                                                    int* __restrict__ bktbase) {
    __shared__ int s[256];
    int t = threadIdx.x;
    int g = (t < NBUCK) ? gcur[t] : 0;
    s[t] = g; __syncthreads();
#pragma unroll
    for (int off = 1; off < 256; off <<= 1) {
        int x = (t >= off) ? s[t - off] : 0;
        __syncthreads();
        s[t] += x;
        __syncthreads();
    }
    if (t < NBUCK) bktbase[t] = s[t] - g;
}

// ---------------- bucket: per-bucket degrees -> dis + rowptr ----------------
__global__ __launch_bounds__(512) void bucket_kernel(
    const int2* __restrict__ gbin, const int* __restrict__ gcur,
    const int* __restrict__ bktbase, float* __restrict__ dis,
    int* __restrict__ rowptr) {
    __shared__ int ldeg[BUCK_NODES];
    __shared__ int s[512];
    int b = blockIdx.x, t = threadIdx.x;
    for (int i = t; i < BUCK_NODES; i += 512) ldeg[i] = 0;
    __syncthreads();
    int n = gcur[b];
    const int2* mybin = gbin + (size_t)b * BIN_CAP;
    for (int i = t; i < n; i += 512)
        atomicAdd(&ldeg[mybin[i].y - b * BUCK_NODES], 1);
    __syncthreads();
    int d = (t < BUCK_NODES) ? ldeg[t] : 0;
    int v = b * BUCK_NODES + t;
    if (t < BUCK_NODES && v < N_NODES) dis[v] = rsqrtf(1.0f + (float)d);
    s[t] = d;
    __syncthreads();
#pragma unroll
    for (int off = 1; off < 512; off <<= 1) {
        int x = (t >= off) ? s[t - off] : 0;
        __syncthreads();
        s[t] += x;
        __syncthreads();
    }
    if (t < BUCK_NODES && v < N_NODES) rowptr[v] = bktbase[b] + s[t] - d;
    if (b == 0 && t == 0) rowptr[N_NODES] = N_EDGES;
}

// ---------------- binB: per-bucket fine scatter to CSR (1024 threads) ----------------
__global__ __launch_bounds__(1024) void binB_kernel(
    const int2* __restrict__ gbin, const int* __restrict__ gcur,
    const int* __restrict__ rowptr, const float* __restrict__ dis,
    int2* __restrict__ epack) {
    __shared__ int curs[BUCK_NODES];
    int b = blockIdx.x, t = threadIdx.x;
    for (int i = t; i < BUCK_NODES; i += 1024) curs[i] = 0;
    __syncthreads();
    int n = gcur[b];
    const int2* mybin = gbin + (size_t)b * BIN_CAP;
    for (int i = t; i < n; i += 1024) {
        int2 q = mybin[i];
        int local = q.y - b * BUCK_NODES;
        int r = atomicAdd(&curs[local], 1);
        int2 rec;
        rec.x = q.x;
        rec.y = __float_as_int(dis[q.x & 0x1FFFF]);
        epack[rowptr[q.y] + r] = rec;
    }
}

// ---------------- fused layer-1 aggregate + mm2: half2-packed LDS table gather ----------------
// Lanes 0-31 take even edges, 32-63 odd; each lane reads __half2 (channels 2cp,2cp+1).
// One ds_read_b32 serves 2 edges -> half the LDS ops/batches of R16. shfl_xor(32)
// merges parities; epilogue converts pair-layout -> lane=channel via xs staging.
__global__ __launch_bounds__(256) void agg1_mm2_kernel(
    const int2* __restrict__ epack, const int* __restrict__ rowptr,
    const int* __restrict__ combo, const float* __restrict__ dis,
    const __half* __restrict__ TCh, const float* __restrict__ W2,
    const float* __restrict__ b1, __half* __restrict__ h2s) {
    __shared__ __align__(16) __half TCs[NCOMBO * HID];  // 19,584 B
    __shared__ __align__(16) float xs[4][HID];          //  1,024 B
    int t = threadIdx.x;
    {
        const int4* s4 = (const int4*)TCh;
        int4* d4 = (int4*)TCs;
        for (int i = t; i < NCOMBO * HID * 2 / 16; i += 256) d4[i] = s4[i];
    }
    __syncthreads();
    int lane = t & 63, w = t >> 6;
    int h = lane >> 5;            // edge parity handled by this lane
    int cp = lane & 31;           // channel pair (channels 2cp, 2cp+1)
    const __half2* TC2 = (const __half2*)TCs;   // row r at TC2[r*32 + cp]; bank=cp -> conflict-free
    float bias = b1[lane];
    float wcol[HID];
#pragma unroll
    for (int k = 0; k < HID; ++k) wcol[k] = W2[k * HID + lane];
    int v0 = (blockIdx.x * 4 + w) * 4;
#pragma unroll 1
    for (int p = 0; p < 2; ++p) {
        int vA = v0 + 2 * p, vB = vA + 1;
        int eA = __builtin_amdgcn_readfirstlane(rowptr[vA]);
        int mA = __builtin_amdgcn_readfirstlane(rowptr[vA + 1]);
        int eB = mA;
        int mB = __builtin_amdgcn_readfirstlane(rowptr[vB + 1]);
        float2 aA = make_float2(0.f, 0.f), aB = make_float2(0.f, 0.f);
        // paired phase: 2 nodes x 4 half2-loads = 16 edges per iteration
        while (eA + 8 <= mA && eB + 8 <= mB) {
            int2 qA[4], qB[4];
#pragma unroll
            for (int i = 0; i < 4; ++i) {
                qA[i] = epack[eA + 2 * i + h];
                qB[i] = epack[eB + 2 * i + h];
            }
            __half2 tA[4], tB[4];
#pragma unroll
            for (int i = 0; i < 4; ++i) {
                tA[i] = TC2[((unsigned)qA[i].x >> 17) * 32 + cp];
                tB[i] = TC2[((unsigned)qB[i].x >> 17) * 32 + cp];
            }
#pragma unroll
            for (int i = 0; i < 4; ++i) {
                float wA = __int_as_float(qA[i].y);
                float2 fA = __half22float2(tA[i]);
                aA.x = fmaf(wA, fA.x, aA.x);
                aA.y = fmaf(wA, fA.y, aA.y);
                float wB = __int_as_float(qB[i].y);
                float2 fB = __half22float2(tB[i]);
                aB.x = fmaf(wB, fB.x, aB.x);
                aB.y = fmaf(wB, fB.y, aB.y);
            }
            eA += 8; eB += 8;
        }
        // drain A (8 edges / iter)
        while (eA + 8 <= mA) {
            int2 q[4];
#pragma unroll
            for (int i = 0; i < 4; ++i) q[i] = epack[eA + 2 * i + h];
            __half2 tv[4];
#pragma unroll
            for (int i = 0; i < 4; ++i) tv[i] = TC2[((unsigned)q[i].x >> 17) * 32 + cp];
#pragma unroll
            for (int i = 0; i < 4; ++i) {
                float wq = __int_as_float(q[i].y);
                float2 f = __half22float2(tv[i]);
                aA.x = fmaf(wq, f.x, aA.x);
                aA.y = fmaf(wq, f.y, aA.y);
            }
            eA += 8;
        }
        {   // tail A: rem in [0,8)
            int rem = mA - eA;
#pragma unroll
            for (int i = 0; i < 4; ++i) {
                int idx = 2 * i + h;
                if (idx < rem) {
                    int2 q = epack[eA + idx];
                    __half2 tv = TC2[((unsigned)q.x >> 17) * 32 + cp];
                    float2 f = __half22float2(tv);
                    float wq = __int_as_float(q.y);
                    aA.x = fmaf(wq, f.x, aA.x);
                    aA.y = fmaf(wq, f.y, aA.y);
                }
            }
        }
        // drain B
        while (eB + 8 <= mB) {
            int2 q[4];
#pragma unroll
            for (int i = 0; i < 4; ++i) q[i] = epack[eB + 2 * i + h];
            __half2 tv[4];
#pragma unroll
            for (int i = 0; i < 4; ++i) tv[i] = TC2[((unsigned)q[i].x >> 17) * 32 + cp];
#pragma unroll
            for (int i = 0; i < 4; ++i) {
                float wq = __int_as_float(q[i].y);
                float2 f = __half22float2(tv[i]);
                aB.x = fmaf(wq, f.x, aB.x);
                aB.y = fmaf(wq, f.y, aB.y);
            }
            eB += 8;
        }
        {   // tail B
            int rem = mB - eB;
#pragma unroll
            for (int i = 0; i < 4; ++i) {
                int idx = 2 * i + h;
                if (idx < rem) {
                    int2 q = epack[eB + idx];
                    __half2 tv = TC2[((unsigned)q.x >> 17) * 32 + cp];
                    float2 f = __half22float2(tv);
                    float wq = __int_as_float(q.y);
                    aB.x = fmaf(wq, f.x, aB.x);
                    aB.y = fmaf(wq, f.y, aB.y);
                }
            }
        }
        // merge parities: both halves end with the full per-channel sums
        aA.x += __shfl_xor(aA.x, 32, 64);
        aA.y += __shfl_xor(aA.y, 32, 64);
        aB.x += __shfl_xor(aB.x, 32, 64);
        aB.y += __shfl_xor(aB.y, 32, 64);
        // epilogue A: pair-layout -> lane=channel via xs, then mm2
        {
            if (h == 0) { xs[w][2 * cp] = aA.x; xs[w][2 * cp + 1] = aA.y; }
            float vacc = xs[w][lane];                       // wave-coherent
            float dv = dis[vA];
            float hv = __half2float(TCs[combo[vA] * HID + lane]);
            float val = dv * fmaf(hv, dv, vacc) + bias;
            val = val > 0.0f ? val : 0.0f;
            xs[w][lane] = val;
            float acc2 = 0.0f;
#pragma unroll
            for (int k4 = 0; k4 < HID / 4; ++k4) {
                float4 xv = *(const float4*)(&xs[w][k4 * 4]);
                acc2 = fmaf(xv.x, wcol[k4 * 4 + 0], acc2);
                acc2 = fmaf(xv.y, wcol[k4 * 4 + 1], acc2);
                acc2 = fmaf(xv.z, wcol[k4 * 4 + 2], acc2);
                acc2 = fmaf(xv.w, wcol[k4 * 4 + 3], acc2);
            }
            h2s[(size_t)vA * HID + lane] = __float2half_rn(acc2 * dv);
        }
        // epilogue B
        {
            if (h == 0) { xs[w][2 * cp] = aB.x; xs[w][2 * cp + 1] = aB.y; }
            float vacc = xs[w][lane];
            float dv = dis[vB];
            float hv = __half2float(TCs[combo[vB] * HID + lane]);
            float val = dv * fmaf(hv, dv, vacc) + bias;
            val = val > 0.0f ? val : 0.0f;
            xs[w][lane] = val;
            float acc2 = 0.0f;
#pragma unroll
            for (int k4 = 0; k4 < HID / 4; ++k4) {
                float4 xv = *(const float4*)(&xs[w][k4 * 4]);
                acc2 = fmaf(xv.x, wcol[k4 * 4 + 0], acc2);
                acc2 = fmaf(xv.y, wcol[k4 * 4 + 1], acc2);
                acc2 = fmaf(xv.z, wcol[k4 * 4 + 2], acc2);
                acc2 = fmaf(xv.w, wcol[k4 * 4 + 3], acc2);
            }
            h2s[(size_t)vB * HID + lane] = __float2half_rn(acc2 * dv);
        }
    }
}

// ---------------- layer-2 aggregate + pool: paired nodes, prescaled h2s ----------------
__global__ __launch_bounds__(256) void agg2_pool_kernel(
    const int2* __restrict__ epack, const int* __restrict__ rowptr,
    const __half* __restrict__ h2s, const float* __restrict__ dis,
    const float* __restrict__ b2, const int* __restrict__ batch,
    float* __restrict__ pooled) {
    int t = threadIdx.x, lane = t & 63, w = t >> 6;
    int vA = (blockIdx.x * 4 + w) * 2;      // grid 12500: vA,vB always < N_NODES
    int vB = vA + 1;
    int eA = __builtin_amdgcn_readfirstlane(rowptr[vA]);
    int mA = __builtin_amdgcn_readfirstlane(rowptr[vA + 1]);
    int eB = mA;
    int mB = __builtin_amdgcn_readfirstlane(rowptr[vB + 1]);
    float accA = 0.0f, accB = 0.0f;
    while (eA + 8 <= mA && eB + 8 <= mB) {
        int2 qA[8], qB[8];
#pragma unroll
        for (int i = 0; i < 8; ++i) { qA[i] = epack[eA + i]; qB[i] = epack[eB + i]; }
        __half gA[8], gB[8];
#pragma unroll
        for (int i = 0; i < 8; ++i) {
            gA[i] = h2s[(size_t)(qA[i].x & 0x1FFFF) * HID + lane];
            gB[i] = h2s[(size_t)(qB[i].x & 0x1FFFF) * HID + lane];
        }
#pragma unroll
        for (int i = 0; i < 8; ++i) {
            accA += __half2float(gA[i]);
            accB += __half2float(gB[i]);
        }
        eA += 8; eB += 8;
    }
    for (; eA + 8 <= mA; eA += 8) {
        int2 q[8];
#pragma unroll
        for (int i = 0; i < 8; ++i) q[i] = epack[eA + i];
        __half g[8];
#pragma unroll
        for (int i = 0; i < 8; ++i) g[i] = h2s[(size_t)(q[i].x & 0x1FFFF) * HID + lane];
#pragma unroll
        for (int i = 0; i < 8; ++i) accA += __half2float(g[i]);
    }
    for (; eA < mA; ++eA) {
        int2 q = epack[eA];
        accA += __half2float(h2s[(size_t)(q.x & 0x1FFFF) * HID + lane]);
    }
    for (; eB + 8 <= mB; eB += 8) {
        int2 q[8];
#pragma unroll
        for (int i = 0; i < 8; ++i) q[i] = epack[eB + i];
        __half g[8];
#pragma unroll
        for (int i = 0; i < 8; ++i) g[i] = h2s[(size_t)(q[i].x & 0x1FFFF) * HID + lane];
#pragma unroll
        for (int i = 0; i < 8; ++i) accB += __half2float(g[i]);
    }
    for (; eB < mB; ++eB) {
        int2 q = epack[eB];
        accB += __half2float(h2s[(size_t)(q.x & 0x1FFFF) * HID + lane]);
    }
    float bv = b2[lane];
    {
        float dv = dis[vA];
        float self = __half2float(h2s[(size_t)vA * HID + lane]);
        float val = dv * (accA + self) + bv;
        val = val > 0.0f ? val : 0.0f;
        unsafeAtomicAdd(&pooled[batch[vA] * HID + lane], val);
    }
    {
        float dv = dis[vB];
        float self = __half2float(h2s[(size_t)vB * HID + lane]);
        float val = dv * (accB + self) + bv;
        val = val > 0.0f ? val : 0.0f;
        unsafeAtomicAdd(&pooled[batch[vB] * HID + lane], val);
    }
}

// ---------------- logits ----------------
__global__ __launch_bounds__(64) void logits_kernel(
    const float* __restrict__ pooled, const int* __restrict__ cnt,
    const float* __restrict__ Wl, const float* __restrict__ bl,
    float* __restrict__ out) {
    __shared__ float row[HID];
    int g = blockIdx.x, t = threadIdx.x;
    int c = cnt[g]; if (c < 1) c = 1;
    row[t] = pooled[g * HID + t] / (float)c;
    __syncthreads();
    if (t < N_CLASSES) {
        float acc = bl[t];
#pragma unroll
        for (int k = 0; k < HID; ++k) acc = fmaf(row[k], Wl[k * N_CLASSES + t], acc);
        out[g * N_CLASSES + t] = acc;
    }
}

extern "C" void kernel_launch(void* const* d_in, const int* in_sizes, int n_in,
                              void* d_out, int out_size, void* d_ws, size_t ws_size,
                              hipStream_t stream) {
    const int*   shape_id = (const int*)d_in[0];
    const int*   color_id = (const int*)d_in[1];
    const int*   edge_idx = (const int*)d_in[2];
    const int*   batch    = (const int*)d_in[3];
    const float* st       = (const float*)d_in[4];
    const float* ct       = (const float*)d_in[5];
    const float* W1       = (const float*)d_in[6];
    const float* b1       = (const float*)d_in[7];
    const float* W2       = (const float*)d_in[8];
    const float* b2       = (const float*)d_in[9];
    const float* Wl       = (const float*)d_in[10];
    const float* bl       = (const float*)d_in[11];
    float* out = (float*)d_out;

    const int* src = edge_idx;
    const int* dst = edge_idx + N_EDGES;

    // workspace layout
    char* ws = (char*)d_ws;
    int*    combo   = (int*)   (ws + 0);            //   400,384 B
    float*  dis     = (float*) (ws + 400384);       //   400,384 B
    int*    bktbase = (int*)   (ws + 800768);       //     1,024 B
    int*    rowptr  = (int*)   (ws + 1201152);      //   400,384 B
    __half* TCh     = (__half*)(ws + 1603584);      //    19,968 B
    float*  pooled  = (float*) (ws + 1623552);      //   262,144 B
    int*    cnt     = (int*)   (ws + 1885696);      //     4,096 B
    int*    gcur    = (int*)   (ws + 1889792);      //     1,024 B
    int2*   epack   = (int2*)  (ws + 1890816);      // 12,800,000 B
    int2*   gbin    = (int2*)  (ws + 14690816);     // 14,680,064 B
    __half* h2s     = (__half*)(ws + 29370880);     // 12,800,000 B (total ~42.2 MB)

    hipMemsetAsync(pooled, 0, N_GRAPHS * HID * sizeof(float) + N_GRAPHS * sizeof(int), stream);
    hipMemsetAsync(gcur, 0, NBUCK * sizeof(int), stream);

    // 1. per-node combo + per-graph counts
    prep_kernel<<<SCAN_BLOCKS, 256, 0, stream>>>(shape_id, color_id, batch, combo, cnt);

    // 2. combined (shape,color)->h1 table (fp16)
    tc_kernel<<<NCOMBO, 64, 0, stream>>>(st, ct, W1, TCh);

    // 3. bin edges by dst-bucket
    binA_kernel<<<(N_EDGES + EPB - 1) / EPB, 512, 0, stream>>>(src, dst, combo, gcur, gbin);

    // 4. bucket bases from gcur
    bscan_kernel<<<1, 256, 0, stream>>>(gcur, bktbase);

    // 5. per-bucket degrees -> dis + rowptr
    bucket_kernel<<<NBUCK, 512, 0, stream>>>(gbin, gcur, bktbase, dis, rowptr);

    // 6. per-bucket scatter to CSR (1024 thr)
    binB_kernel<<<NBUCK, 1024, 0, stream>>>(gbin, gcur, rowptr, dis, epack);

    // 7. fused layer-1 aggregate + mm2 -> h2s (half2-packed LDS gather, paired nodes)
    agg1_mm2_kernel<<<6250, 256, 0, stream>>>(epack, rowptr, combo, dis, TCh, W2, b1, h2s);

    // 8. layer-2 aggregate + pool (paired nodes)
    agg2_pool_kernel<<<N_NODES / 8, 256, 0, stream>>>(epack, rowptr, h2s, dis, b2,
                                                      batch, pooled);

    // 9. logits
    logits_kernel<<<N_GRAPHS, 64, 0, stream>>>(pooled, cnt, Wl, bl, out);
}

// Round 18
// 285.356 us; speedup vs baseline: 1.0600x; 1.0600x over previous
//
#include <hip/hip_runtime.h>
#include <hip/hip_bf16.h>
#include <hip/hip_fp16.h>

#define N_NODES   100000
#define N_EDGES   1600000
#define N_GRAPHS  1024
#define EMB       32
#define HID       64
#define N_CLASSES 10
#define SCAN_BLOCKS 391   // ceil(100000/256)
#define NCOMBO 153        // 17 shape ids x 9 color ids
#define BUCK_NODES 448    // nodes per dst-bucket
#define NBUCK 224         // ceil(100000/448)
#define BIN_CAP 8192      // per-bucket staging capacity (mean 7143, +12 sigma)
#define EPB 4096          // edges per binA block

// ---------------- prep: combo[v], per-graph counts ----------------
__global__ __launch_bounds__(256) void prep_kernel(
    const int* __restrict__ sid, const int* __restrict__ cid,
    const int* __restrict__ batch, int* __restrict__ combo, int* __restrict__ cnt) {
    int v = blockIdx.x * 256 + threadIdx.x;
    if (v < N_NODES) {
        combo[v] = sid[v] * 9 + cid[v];
        atomicAdd(&cnt[batch[v]], 1);
    }
}

// ---------------- combined table (fp16): TCh[s*9+c][j] = (st[s]@W1)[j] + (ct[c]@W1)[j] ----------------
__global__ __launch_bounds__(64) void tc_kernel(
    const float* __restrict__ st, const float* __restrict__ ct,
    const float* __restrict__ W1, __half* __restrict__ TCh) {
    int r = blockIdx.x, j = threadIdx.x;
    int s = r / 9, c = r % 9;
    float acc = 0.0f;
    if (s != 0) {
#pragma unroll
        for (int k = 0; k < EMB; ++k) acc = fmaf(st[s * EMB + k], W1[k * HID + j], acc);
    }
    if (c != 0) {
#pragma unroll
        for (int k = 0; k < EMB; ++k) acc = fmaf(ct[c * EMB + k], W1[k * HID + j], acc);
    }
    TCh[r * HID + j] = __float2half_rn(acc);
}

// ---------------- binA: block-local counting sort by dst-bucket, chunked flush ----------------
__global__ __launch_bounds__(512) void binA_kernel(
    const int* __restrict__ src, const int* __restrict__ dst,
    const int* __restrict__ combo, int* __restrict__ gcur,
    int2* __restrict__ gbin) {
    __shared__ int2 stg[EPB];            // 32 KB
    __shared__ int hist[NBUCK];
    __shared__ int base[NBUCK + 1];
    __shared__ int gstart[NBUCK];
    __shared__ int scanbuf[256];
    int t = threadIdx.x;
    int e0 = blockIdx.x * EPB;
    for (int i = t; i < NBUCK; i += 512) hist[i] = 0;
    __syncthreads();

    int2 myq[8];
    int mybo[8];
#pragma unroll
    for (int i = 0; i < 8; ++i) {
        int e = e0 + t + i * 512;
        if (e < N_EDGES) {
            int d = dst[e];
            int s = src[e];
            unsigned b = (unsigned)d / BUCK_NODES;
            int off = atomicAdd(&hist[b], 1);
            myq[i].x = s | (combo[s] << 17);
            myq[i].y = d;
            mybo[i] = (int)(b << 16) | off;
        } else {
            mybo[i] = -1;
        }
    }
    __syncthreads();

    int h = (t < NBUCK) ? hist[t] : 0;
    if (t < 256) scanbuf[t] = h;
    __syncthreads();
#pragma unroll
    for (int off = 1; off < 256; off <<= 1) {
        int x = (t < 256 && t >= off) ? scanbuf[t - off] : 0;
        __syncthreads();
        if (t < 256) scanbuf[t] += x;
        __syncthreads();
    }
    if (t < NBUCK) base[t] = scanbuf[t] - h;
    if (t == 0) base[NBUCK] = scanbuf[255];
    __syncthreads();
#pragma unroll
    for (int i = 0; i < 8; ++i) {
        if (mybo[i] >= 0) {
            int b = mybo[i] >> 16, off = mybo[i] & 0xFFFF;
            stg[base[b] + off] = myq[i];
        }
    }
    if (t < NBUCK) {
        int n = hist[t];
        gstart[t] = n ? atomicAdd(&gcur[t], n) : 0;
    }
    __syncthreads();
    int total = base[NBUCK];
    for (int i = t; i < total; i += 512) {
        int2 q = stg[i];
        unsigned b = (unsigned)q.y / BUCK_NODES;
        gbin[(size_t)b * BIN_CAP + gstart[b] + (i - base[b])] = q;
    }
}

// ---------------- bscan: exclusive scan of gcur[224] -> bktbase ----------------
__global__ __launch_bounds__(256) void bscan_kernel(const int* __restrict__ gcur,
                                                    int* __restrict__ bktbase) {
    __shared__ int s[256];
    int t = threadIdx.x;
    int g = (t < NBUCK) ? gcur[t] : 0;
    s[t] = g; __syncthreads();
#pragma unroll
    for (int off = 1; off < 256; off <<= 1) {
        int x = (t >= off) ? s[t - off] : 0;
        __syncthreads();
        s[t] += x;
        __syncthreads();
    }
    if (t < NBUCK) bktbase[t] = s[t] - g;
}

// ---------------- bucket: per-bucket degrees -> dis + rowptr ----------------
__global__ __launch_bounds__(512) void bucket_kernel(
    const int2* __restrict__ gbin, const int* __restrict__ gcur,
    const int* __restrict__ bktbase, float* __restrict__ dis,
    int* __restrict__ rowptr) {
    __shared__ int ldeg[BUCK_NODES];
    __shared__ int s[512];
    int b = blockIdx.x, t = threadIdx.x;
    for (int i = t; i < BUCK_NODES; i += 512) ldeg[i] = 0;
    __syncthreads();
    int n = gcur[b];
    const int2* mybin = gbin + (size_t)b * BIN_CAP;
    for (int i = t; i < n; i += 512)
        atomicAdd(&ldeg[mybin[i].y - b * BUCK_NODES], 1);
    __syncthreads();
    int d = (t < BUCK_NODES) ? ldeg[t] : 0;
    int v = b * BUCK_NODES + t;
    if (t < BUCK_NODES && v < N_NODES) dis[v] = rsqrtf(1.0f + (float)d);
    s[t] = d;
    __syncthreads();
#pragma unroll
    for (int off = 1; off < 512; off <<= 1) {
        int x = (t >= off) ? s[t - off] : 0;
        __syncthreads();
        s[t] += x;
        __syncthreads();
    }
    if (t < BUCK_NODES && v < N_NODES) rowptr[v] = bktbase[b] + s[t] - d;
    if (b == 0 && t == 0) rowptr[N_NODES] = N_EDGES;
}

// ---------------- binB: per-bucket fine scatter to CSR (1024 threads) ----------------
__global__ __launch_bounds__(1024) void binB_kernel(
    const int2* __restrict__ gbin, const int* __restrict__ gcur,
    const int* __restrict__ rowptr, const float* __restrict__ dis,
    int2* __restrict__ epack) {
    __shared__ int curs[BUCK_NODES];
    int b = blockIdx.x, t = threadIdx.x;
    for (int i = t; i < BUCK_NODES; i += 1024) curs[i] = 0;
    __syncthreads();
    int n = gcur[b];
    const int2* mybin = gbin + (size_t)b * BIN_CAP;
    for (int i = t; i < n; i += 1024) {
        int2 q = mybin[i];
        int local = q.y - b * BUCK_NODES;
        int r = atomicAdd(&curs[local], 1);
        int2 rec;
        rec.x = q.x;
        rec.y = __float_as_int(dis[q.x & 0x1FFFF]);
        epack[rowptr[q.y] + r] = rec;
    }
}

// ---------------- fused layer-1 aggregate + mm2 (R16 loop, 1 pair per wave) ----------------
__global__ __launch_bounds__(256) void agg1_mm2_kernel(
    const int2* __restrict__ epack, const int* __restrict__ rowptr,
    const int* __restrict__ combo, const float* __restrict__ dis,
    const __half* __restrict__ TCh, const float* __restrict__ W2,
    const float* __restrict__ b1, __half* __restrict__ h2s) {
    __shared__ __align__(16) __half TCs[NCOMBO * HID];  // 19,584 B
    __shared__ __align__(16) float xs[4][HID];          //  1,024 B
    int t = threadIdx.x;
    {
        const int4* s4 = (const int4*)TCh;
        int4* d4 = (int4*)TCs;
        for (int i = t; i < NCOMBO * HID * 2 / 16; i += 256) d4[i] = s4[i];
    }
    __syncthreads();
    int lane = t & 63, w = t >> 6;
    float bias = b1[lane];
    float wcol[HID];
#pragma unroll
    for (int k = 0; k < HID; ++k) wcol[k] = W2[k * HID + lane];
    int vA = (blockIdx.x * 4 + w) * 2;      // grid 12500: one pair per wave
    int vB = vA + 1;
    int eA = __builtin_amdgcn_readfirstlane(rowptr[vA]);
    int mA = __builtin_amdgcn_readfirstlane(rowptr[vA + 1]);
    int eB = mA;
    int mB = __builtin_amdgcn_readfirstlane(rowptr[vB + 1]);
    float accA = 0.0f, accB = 0.0f;
    // paired phase: two 8-deep LDS-gather pipelines in flight
    while (eA + 8 <= mA && eB + 8 <= mB) {
        int2 qA[8], qB[8];
#pragma unroll
        for (int i = 0; i < 8; ++i) { qA[i] = epack[eA + i]; qB[i] = epack[eB + i]; }
        __half tA[8], tB[8];
#pragma unroll
        for (int i = 0; i < 8; ++i) {
            tA[i] = TCs[((unsigned)qA[i].x >> 17) * HID + lane];
            tB[i] = TCs[((unsigned)qB[i].x >> 17) * HID + lane];
        }
#pragma unroll
        for (int i = 0; i < 8; ++i) {
            accA = fmaf(__int_as_float(qA[i].y), __half2float(tA[i]), accA);
            accB = fmaf(__int_as_float(qB[i].y), __half2float(tB[i]), accB);
        }
        eA += 8; eB += 8;
    }
    // drain A
    for (; eA + 8 <= mA; eA += 8) {
        int2 q[8];
#pragma unroll
        for (int i = 0; i < 8; ++i) q[i] = epack[eA + i];
        __half tv[8];
#pragma unroll
        for (int i = 0; i < 8; ++i) tv[i] = TCs[((unsigned)q[i].x >> 17) * HID + lane];
#pragma unroll
        for (int i = 0; i < 8; ++i)
            accA = fmaf(__int_as_float(q[i].y), __half2float(tv[i]), accA);
    }
    for (; eA < mA; ++eA) {
        int2 q = epack[eA];
        accA = fmaf(__int_as_float(q.y),
                    __half2float(TCs[((unsigned)q.x >> 17) * HID + lane]), accA);
    }
    // drain B
    for (; eB + 8 <= mB; eB += 8) {
        int2 q[8];
#pragma unroll
        for (int i = 0; i < 8; ++i) q[i] = epack[eB + i];
        __half tv[8];
#pragma unroll
        for (int i = 0; i < 8; ++i) tv[i] = TCs[((unsigned)q[i].x >> 17) * HID + lane];
#pragma unroll
        for (int i = 0; i < 8; ++i)
            accB = fmaf(__int_as_float(q[i].y), __half2float(tv[i]), accB);
    }
    for (; eB < mB; ++eB) {
        int2 q = epack[eB];
        accB = fmaf(__int_as_float(q.y),
                    __half2float(TCs[((unsigned)q.x >> 17) * HID + lane]), accB);
    }
    // epilogue A
    {
        float dv = dis[vA];
        float hv = __half2float(TCs[combo[vA] * HID + lane]);
        float val = dv * fmaf(hv, dv, accA) + bias;
        val = val > 0.0f ? val : 0.0f;
        xs[w][lane] = val;
        float acc2 = 0.0f;
#pragma unroll
        for (int k4 = 0; k4 < HID / 4; ++k4) {
            float4 xv = *(const float4*)(&xs[w][k4 * 4]);
            acc2 = fmaf(xv.x, wcol[k4 * 4 + 0], acc2);
            acc2 = fmaf(xv.y, wcol[k4 * 4 + 1], acc2);
            acc2 = fmaf(xv.z, wcol[k4 * 4 + 2], acc2);
            acc2 = fmaf(xv.w, wcol[k4 * 4 + 3], acc2);
        }
        h2s[(size_t)vA * HID + lane] = __float2half_rn(acc2 * dv);
    }
    // epilogue B
    {
        float dv = dis[vB];
        float hv = __half2float(TCs[combo[vB] * HID + lane]);
        float val = dv * fmaf(hv, dv, accB) + bias;
        val = val > 0.0f ? val : 0.0f;
        xs[w][lane] = val;
        float acc2 = 0.0f;
#pragma unroll
        for (int k4 = 0; k4 < HID / 4; ++k4) {
            float4 xv = *(const float4*)(&xs[w][k4 * 4]);
            acc2 = fmaf(xv.x, wcol[k4 * 4 + 0], acc2);
            acc2 = fmaf(xv.y, wcol[k4 * 4 + 1], acc2);
            acc2 = fmaf(xv.z, wcol[k4 * 4 + 2], acc2);
            acc2 = fmaf(xv.w, wcol[k4 * 4 + 3], acc2);
        }
        h2s[(size_t)vB * HID + lane] = __float2half_rn(acc2 * dv);
    }
}

// ---------------- layer-2 aggregate + pool: paired nodes, merged same-graph atomic ----------------
__global__ __launch_bounds__(256) void agg2_pool_kernel(
    const int2* __restrict__ epack, const int* __restrict__ rowptr,
    const __half* __restrict__ h2s, const float* __restrict__ dis,
    const float* __restrict__ b2, const int* __restrict__ batch,
    float* __restrict__ pooled) {
    int t = threadIdx.x, lane = t & 63, w = t >> 6;
    int vA = (blockIdx.x * 4 + w) * 2;      // grid 12500: vA,vB always < N_NODES
    int vB = vA + 1;
    int eA = __builtin_amdgcn_readfirstlane(rowptr[vA]);
    int mA = __builtin_amdgcn_readfirstlane(rowptr[vA + 1]);
    int eB = mA;
    int mB = __builtin_amdgcn_readfirstlane(rowptr[vB + 1]);
    float accA = 0.0f, accB = 0.0f;
    while (eA + 8 <= mA && eB + 8 <= mB) {
        int2 qA[8], qB[8];
#pragma unroll
        for (int i = 0; i < 8; ++i) { qA[i] = epack[eA + i]; qB[i] = epack[eB + i]; }
        __half gA[8], gB[8];
#pragma unroll
        for (int i = 0; i < 8; ++i) {
            gA[i] = h2s[(size_t)(qA[i].x & 0x1FFFF) * HID + lane];
            gB[i] = h2s[(size_t)(qB[i].x & 0x1FFFF) * HID + lane];
        }
#pragma unroll
        for (int i = 0; i < 8; ++i) {
            accA += __half2float(gA[i]);
            accB += __half2float(gB[i]);
        }
        eA += 8; eB += 8;
    }
    for (; eA + 8 <= mA; eA += 8) {
        int2 q[8];
#pragma unroll
        for (int i = 0; i < 8; ++i) q[i] = epack[eA + i];
        __half g[8];
#pragma unroll
        for (int i = 0; i < 8; ++i) g[i] = h2s[(size_t)(q[i].x & 0x1FFFF) * HID + lane];
#pragma unroll
        for (int i = 0; i < 8; ++i) accA += __half2float(g[i]);
    }
    for (; eA < mA; ++eA) {
        int2 q = epack[eA];
        accA += __half2float(h2s[(size_t)(q.x & 0x1FFFF) * HID + lane]);
    }
    for (; eB + 8 <= mB; eB += 8) {
        int2 q[8];
#pragma unroll
        for (int i = 0; i < 8; ++i) q[i] = epack[eB + i];
        __half g[8];
#pragma unroll
        for (int i = 0; i < 8; ++i) g[i] = h2s[(size_t)(q[i].x & 0x1FFFF) * HID + lane];
#pragma unroll
        for (int i = 0; i < 8; ++i) accB += __half2float(g[i]);
    }
    for (; eB < mB; ++eB) {
        int2 q = epack[eB];
        accB += __half2float(h2s[(size_t)(q.x & 0x1FFFF) * HID + lane]);
    }
    float bv = b2[lane];
    float dvA = dis[vA];
    float selfA = __half2float(h2s[(size_t)vA * HID + lane]);
    float valA = dvA * (accA + selfA) + bv;
    valA = valA > 0.0f ? valA : 0.0f;
    float dvB = dis[vB];
    float selfB = __half2float(h2s[(size_t)vB * HID + lane]);
    float valB = dvB * (accB + selfB) + bv;
    valB = valB > 0.0f ? valB : 0.0f;
    int gA = batch[vA], gB = batch[vB];
    if (gA == gB) {
        unsafeAtomicAdd(&pooled[gA * HID + lane], valA + valB);  // merged: half the atomic lines
    } else {
        unsafeAtomicAdd(&pooled[gA * HID + lane], valA);
        unsafeAtomicAdd(&pooled[gB * HID + lane], valB);
    }
}

// ---------------- logits ----------------
__global__ __launch_bounds__(64) void logits_kernel(
    const float* __restrict__ pooled, const int* __restrict__ cnt,
    const float* __restrict__ Wl, const float* __restrict__ bl,
    float* __restrict__ out) {
    __shared__ float row[HID];
    int g = blockIdx.x, t = threadIdx.x;
    int c = cnt[g]; if (c < 1) c = 1;
    row[t] = pooled[g * HID + t] / (float)c;
    __syncthreads();
    if (t < N_CLASSES) {
        float acc = bl[t];
#pragma unroll
        for (int k = 0; k < HID; ++k) acc = fmaf(row[k], Wl[k * N_CLASSES + t], acc);
        out[g * N_CLASSES + t] = acc;
    }
}

extern "C" void kernel_launch(void* const* d_in, const int* in_sizes, int n_in,
                              void* d_out, int out_size, void* d_ws, size_t ws_size,
                              hipStream_t stream) {
    const int*   shape_id = (const int*)d_in[0];
    const int*   color_id = (const int*)d_in[1];
    const int*   edge_idx = (const int*)d_in[2];
    const int*   batch    = (const int*)d_in[3];
    const float* st       = (const float*)d_in[4];
    const float* ct       = (const float*)d_in[5];
    const float* W1       = (const float*)d_in[6];
    const float* b1       = (const float*)d_in[7];
    const float* W2       = (const float*)d_in[8];
    const float* b2       = (const float*)d_in[9];
    const float* Wl       = (const float*)d_in[10];
    const float* bl       = (const float*)d_in[11];
    float* out = (float*)d_out;

    const int* src = edge_idx;
    const int* dst = edge_idx + N_EDGES;

    // workspace layout
    char* ws = (char*)d_ws;
    int*    combo   = (int*)   (ws + 0);            //   400,384 B
    float*  dis     = (float*) (ws + 400384);       //   400,384 B
    int*    bktbase = (int*)   (ws + 800768);       //     1,024 B
    int*    rowptr  = (int*)   (ws + 1201152);      //   400,384 B
    __half* TCh     = (__half*)(ws + 1603584);      //    19,968 B
    float*  pooled  = (float*) (ws + 1623552);      //   262,144 B
    int*    cnt     = (int*)   (ws + 1885696);      //     4,096 B
    int*    gcur    = (int*)   (ws + 1889792);      //     1,024 B
    int2*   epack   = (int2*)  (ws + 1890816);      // 12,800,000 B
    int2*   gbin    = (int2*)  (ws + 14690816);     // 14,680,064 B
    __half* h2s     = (__half*)(ws + 29370880);     // 12,800,000 B (total ~42.2 MB)

    hipMemsetAsync(pooled, 0, N_GRAPHS * HID * sizeof(float) + N_GRAPHS * sizeof(int), stream);
    hipMemsetAsync(gcur, 0, NBUCK * sizeof(int), stream);

    // 1. per-node combo + per-graph counts
    prep_kernel<<<SCAN_BLOCKS, 256, 0, stream>>>(shape_id, color_id, batch, combo, cnt);

    // 2. combined (shape,color)->h1 table (fp16)
    tc_kernel<<<NCOMBO, 64, 0, stream>>>(st, ct, W1, TCh);

    // 3. bin edges by dst-bucket
    binA_kernel<<<(N_EDGES + EPB - 1) / EPB, 512, 0, stream>>>(src, dst, combo, gcur, gbin);

    // 4. bucket bases from gcur
    bscan_kernel<<<1, 256, 0, stream>>>(gcur, bktbase);

    // 5. per-bucket degrees -> dis + rowptr
    bucket_kernel<<<NBUCK, 512, 0, stream>>>(gbin, gcur, bktbase, dis, rowptr);

    // 6. per-bucket scatter to CSR (1024 thr)
    binB_kernel<<<NBUCK, 1024, 0, stream>>>(gbin, gcur, rowptr, dis, epack);

    // 7. fused layer-1 aggregate + mm2 -> h2s (R16 loop, 1 pair/wave, grid 12500)
    agg1_mm2_kernel<<<12500, 256, 0, stream>>>(epack, rowptr, combo, dis, TCh, W2, b1, h2s);

    // 8. layer-2 aggregate + pool (paired nodes, merged same-graph atomic)
    agg2_pool_kernel<<<N_NODES / 8, 256, 0, stream>>>(epack, rowptr, h2s, dis, b2,
                                                      batch, pooled);

    // 9. logits
    logits_kernel<<<N_GRAPHS, 64, 0, stream>>>(pooled, cnt, Wl, bl, out);
}

// Round 19
// 274.308 us; speedup vs baseline: 1.1027x; 1.0403x over previous
//
#include <hip/hip_runtime.h>
#include <hip/hip_bf16.h>
#include <hip/hip_fp16.h>

#define N_NODES   100000
#define N_EDGES   1600000
#define N_GRAPHS  1024
#define EMB       32
#define HID       64
#define N_CLASSES 10
#define SCAN_BLOCKS 391   // ceil(100000/256)
#define NCOMBO 153        // 17 shape ids x 9 color ids
#define BUCK_NODES 448    // nodes per dst-bucket
#define NBUCK 224         // ceil(100000/448)
#define BIN_CAP 8192      // per-bucket staging capacity (mean 7143, +12 sigma)
#define EPB 4096          // edges per binA block

// ---------------- prep: combo[v], per-graph counts ----------------
__global__ __launch_bounds__(256) void prep_kernel(
    const int* __restrict__ sid, const int* __restrict__ cid,
    const int* __restrict__ batch, int* __restrict__ combo, int* __restrict__ cnt) {
    int v = blockIdx.x * 256 + threadIdx.x;
    if (v < N_NODES) {
        combo[v] = sid[v] * 9 + cid[v];
        atomicAdd(&cnt[batch[v]], 1);
    }
}

// ---------------- combined table (fp16): TCh[s*9+c][j] = (st[s]@W1)[j] + (ct[c]@W1)[j] ----------------
__global__ __launch_bounds__(64) void tc_kernel(
    const float* __restrict__ st, const float* __restrict__ ct,
    const float* __restrict__ W1, __half* __restrict__ TCh) {
    int r = blockIdx.x, j = threadIdx.x;
    int s = r / 9, c = r % 9;
    float acc = 0.0f;
    if (s != 0) {
#pragma unroll
        for (int k = 0; k < EMB; ++k) acc = fmaf(st[s * EMB + k], W1[k * HID + j], acc);
    }
    if (c != 0) {
#pragma unroll
        for (int k = 0; k < EMB; ++k) acc = fmaf(ct[c * EMB + k], W1[k * HID + j], acc);
    }
    TCh[r * HID + j] = __float2half_rn(acc);
}

// ---------------- binA: block-local counting sort by dst-bucket, chunked flush ----------------
__global__ __launch_bounds__(512) void binA_kernel(
    const int* __restrict__ src, const int* __restrict__ dst,
    const int* __restrict__ combo, int* __restrict__ gcur,
    int2* __restrict__ gbin) {
    __shared__ int2 stg[EPB];            // 32 KB
    __shared__ int hist[NBUCK];
    __shared__ int base[NBUCK + 1];
    __shared__ int gstart[NBUCK];
    __shared__ int scanbuf[256];
    int t = threadIdx.x;
    int e0 = blockIdx.x * EPB;
    for (int i = t; i < NBUCK; i += 512) hist[i] = 0;
    __syncthreads();

    int2 myq[8];
    int mybo[8];
#pragma unroll
    for (int i = 0; i < 8; ++i) {
        int e = e0 + t + i * 512;
        if (e < N_EDGES) {
            int d = dst[e];
            int s = src[e];
            unsigned b = (unsigned)d / BUCK_NODES;
            int off = atomicAdd(&hist[b], 1);
            myq[i].x = s | (combo[s] << 17);
            myq[i].y = d;
            mybo[i] = (int)(b << 16) | off;
        } else {
            mybo[i] = -1;
        }
    }
    __syncthreads();

    int h = (t < NBUCK) ? hist[t] : 0;
    if (t < 256) scanbuf[t] = h;
    __syncthreads();
#pragma unroll
    for (int off = 1; off < 256; off <<= 1) {
        int x = (t < 256 && t >= off) ? scanbuf[t - off] : 0;
        __syncthreads();
        if (t < 256) scanbuf[t] += x;
        __syncthreads();
    }
    if (t < NBUCK) base[t] = scanbuf[t] - h;
    if (t == 0) base[NBUCK] = scanbuf[255];
    __syncthreads();
#pragma unroll
    for (int i = 0; i < 8; ++i) {
        if (mybo[i] >= 0) {
            int b = mybo[i] >> 16, off = mybo[i] & 0xFFFF;
            stg[base[b] + off] = myq[i];
        }
    }
    if (t < NBUCK) {
        int n = hist[t];
        gstart[t] = n ? atomicAdd(&gcur[t], n) : 0;
    }
    __syncthreads();
    int total = base[NBUCK];
    for (int i = t; i < total; i += 512) {
        int2 q = stg[i];
        unsigned b = (unsigned)q.y / BUCK_NODES;
        gbin[(size_t)b * BIN_CAP + gstart[b] + (i - base[b])] = q;
    }
}

// ---------------- bscan: exclusive scan of gcur[224] -> bktbase ----------------
__global__ __launch_bounds__(256) void bscan_kernel(const int* __restrict__ gcur,
                                                    int* __restrict__ bktbase) {
    __shared__ int s[256];
    int t = threadIdx.x;
    int g = (t < NBUCK) ? gcur[t] : 0;
    s[t] = g; __syncthreads();
#pragma unroll
    for (int off = 1; off < 256; off <<= 1) {
        int x = (t >= off) ? s[t - off] : 0;
        __syncthreads();
        s[t] += x;
        __syncthreads();
    }
    if (t < NBUCK) bktbase[t] = s[t] - g;
}

// ---------------- bucket: per-bucket degrees -> dis + rowptr ----------------
__global__ __launch_bounds__(512) void bucket_kernel(
    const int2* __restrict__ gbin, const int* __restrict__ gcur,
    const int* __restrict__ bktbase, float* __restrict__ dis,
    int* __restrict__ rowptr) {
    __shared__ int ldeg[BUCK_NODES];
    __shared__ int s[512];
    int b = blockIdx.x, t = threadIdx.x;
    for (int i = t; i < BUCK_NODES; i += 512) ldeg[i] = 0;
    __syncthreads();
    int n = gcur[b];
    const int2* mybin = gbin + (size_t)b * BIN_CAP;
    for (int i = t; i < n; i += 512)
        atomicAdd(&ldeg[mybin[i].y - b * BUCK_NODES], 1);
    __syncthreads();
    int d = (t < BUCK_NODES) ? ldeg[t] : 0;
    int v = b * BUCK_NODES + t;
    if (t < BUCK_NODES && v < N_NODES) dis[v] = rsqrtf(1.0f + (float)d);
    s[t] = d;
    __syncthreads();
#pragma unroll
    for (int off = 1; off < 512; off <<= 1) {
        int x = (t >= off) ? s[t - off] : 0;
        __syncthreads();
        s[t] += x;
        __syncthreads();
    }
    if (t < BUCK_NODES && v < N_NODES) rowptr[v] = bktbase[b] + s[t] - d;
    if (b == 0 && t == 0) rowptr[N_NODES] = N_EDGES;
}

// ---------------- binB: per-bucket fine scatter to CSR (1024 threads) ----------------
__global__ __launch_bounds__(1024) void binB_kernel(
    const int2* __restrict__ gbin, const int* __restrict__ gcur,
    const int* __restrict__ rowptr, const float* __restrict__ dis,
    int2* __restrict__ epack) {
    __shared__ int curs[BUCK_NODES];
    int b = blockIdx.x, t = threadIdx.x;
    for (int i = t; i < BUCK_NODES; i += 1024) curs[i] = 0;
    __syncthreads();
    int n = gcur[b];
    const int2* mybin = gbin + (size_t)b * BIN_CAP;
    for (int i = t; i < n; i += 1024) {
        int2 q = mybin[i];
        int local = q.y - b * BUCK_NODES;
        int r = atomicAdd(&curs[local], 1);
        int2 rec;
        rec.x = q.x;
        rec.y = __float_as_int(dis[q.x & 0x1FFFF]);
        epack[rowptr[q.y] + r] = rec;
    }
}

// ---------------- fused layer-1 aggregate + mm2 (R16: 2 pairs per wave, grid 6250) ----------------
__global__ __launch_bounds__(256) void agg1_mm2_kernel(
    const int2* __restrict__ epack, const int* __restrict__ rowptr,
    const int* __restrict__ combo, const float* __restrict__ dis,
    const __half* __restrict__ TCh, const float* __restrict__ W2,
    const float* __restrict__ b1, __half* __restrict__ h2s) {
    __shared__ __align__(16) __half TCs[NCOMBO * HID];  // 19,584 B
    __shared__ __align__(16) float xs[4][HID];          //  1,024 B
    int t = threadIdx.x;
    {
        const int4* s4 = (const int4*)TCh;
        int4* d4 = (int4*)TCs;
        for (int i = t; i < NCOMBO * HID * 2 / 16; i += 256) d4[i] = s4[i];
    }
    __syncthreads();
    int lane = t & 63, w = t >> 6;
    float bias = b1[lane];
    float wcol[HID];
#pragma unroll
    for (int k = 0; k < HID; ++k) wcol[k] = W2[k * HID + lane];
    int v0 = (blockIdx.x * 4 + w) * 4;
#pragma unroll 1
    for (int p = 0; p < 2; ++p) {
        int vA = v0 + 2 * p, vB = vA + 1;
        int eA = __builtin_amdgcn_readfirstlane(rowptr[vA]);
        int mA = __builtin_amdgcn_readfirstlane(rowptr[vA + 1]);
        int eB = mA;
        int mB = __builtin_amdgcn_readfirstlane(rowptr[vB + 1]);
        float accA = 0.0f, accB = 0.0f;
        // paired phase: two 8-deep LDS-gather pipelines in flight
        while (eA + 8 <= mA && eB + 8 <= mB) {
            int2 qA[8], qB[8];
#pragma unroll
            for (int i = 0; i < 8; ++i) { qA[i] = epack[eA + i]; qB[i] = epack[eB + i]; }
            __half tA[8], tB[8];
#pragma unroll
            for (int i = 0; i < 8; ++i) {
                tA[i] = TCs[((unsigned)qA[i].x >> 17) * HID + lane];
                tB[i] = TCs[((unsigned)qB[i].x >> 17) * HID + lane];
            }
#pragma unroll
            for (int i = 0; i < 8; ++i) {
                accA = fmaf(__int_as_float(qA[i].y), __half2float(tA[i]), accA);
                accB = fmaf(__int_as_float(qB[i].y), __half2float(tB[i]), accB);
            }
            eA += 8; eB += 8;
        }
        // drain A
        for (; eA + 8 <= mA; eA += 8) {
            int2 q[8];
#pragma unroll
            for (int i = 0; i < 8; ++i) q[i] = epack[eA + i];
            __half tv[8];
#pragma unroll
            for (int i = 0; i < 8; ++i) tv[i] = TCs[((unsigned)q[i].x >> 17) * HID + lane];
#pragma unroll
            for (int i = 0; i < 8; ++i)
                accA = fmaf(__int_as_float(q[i].y), __half2float(tv[i]), accA);
        }
        for (; eA < mA; ++eA) {
            int2 q = epack[eA];
            accA = fmaf(__int_as_float(q.y),
                        __half2float(TCs[((unsigned)q.x >> 17) * HID + lane]), accA);
        }
        // drain B
        for (; eB + 8 <= mB; eB += 8) {
            int2 q[8];
#pragma unroll
            for (int i = 0; i < 8; ++i) q[i] = epack[eB + i];
            __half tv[8];
#pragma unroll
            for (int i = 0; i < 8; ++i) tv[i] = TCs[((unsigned)q[i].x >> 17) * HID + lane];
#pragma unroll
            for (int i = 0; i < 8; ++i)
                accB = fmaf(__int_as_float(q[i].y), __half2float(tv[i]), accB);
        }
        for (; eB < mB; ++eB) {
            int2 q = epack[eB];
            accB = fmaf(__int_as_float(q.y),
                        __half2float(TCs[((unsigned)q.x >> 17) * HID + lane]), accB);
        }
        // epilogue A
        {
            float dv = dis[vA];
            float hv = __half2float(TCs[combo[vA] * HID + lane]);
            float val = dv * fmaf(hv, dv, accA) + bias;
            val = val > 0.0f ? val : 0.0f;
            xs[w][lane] = val;
            float acc2 = 0.0f;
#pragma unroll
            for (int k4 = 0; k4 < HID / 4; ++k4) {
                float4 xv = *(const float4*)(&xs[w][k4 * 4]);
                acc2 = fmaf(xv.x, wcol[k4 * 4 + 0], acc2);
                acc2 = fmaf(xv.y, wcol[k4 * 4 + 1], acc2);
                acc2 = fmaf(xv.z, wcol[k4 * 4 + 2], acc2);
                acc2 = fmaf(xv.w, wcol[k4 * 4 + 3], acc2);
            }
            h2s[(size_t)vA * HID + lane] = __float2half_rn(acc2 * dv);
        }
        // epilogue B
        {
            float dv = dis[vB];
            float hv = __half2float(TCs[combo[vB] * HID + lane]);
            float val = dv * fmaf(hv, dv, accB) + bias;
            val = val > 0.0f ? val : 0.0f;
            xs[w][lane] = val;
            float acc2 = 0.0f;
#pragma unroll
            for (int k4 = 0; k4 < HID / 4; ++k4) {
                float4 xv = *(const float4*)(&xs[w][k4 * 4]);
                acc2 = fmaf(xv.x, wcol[k4 * 4 + 0], acc2);
                acc2 = fmaf(xv.y, wcol[k4 * 4 + 1], acc2);
                acc2 = fmaf(xv.z, wcol[k4 * 4 + 2], acc2);
                acc2 = fmaf(xv.w, wcol[k4 * 4 + 3], acc2);
            }
            h2s[(size_t)vB * HID + lane] = __float2half_rn(acc2 * dv);
        }
    }
}

// ---------------- layer-2 aggregate + pool: paired nodes, merged same-graph atomic ----------------
__global__ __launch_bounds__(256) void agg2_pool_kernel(
    const int2* __restrict__ epack, const int* __restrict__ rowptr,
    const __half* __restrict__ h2s, const float* __restrict__ dis,
    const float* __restrict__ b2, const int* __restrict__ batch,
    float* __restrict__ pooled) {
    int t = threadIdx.x, lane = t & 63, w = t >> 6;
    int vA = (blockIdx.x * 4 + w) * 2;      // grid 12500: vA,vB always < N_NODES
    int vB = vA + 1;
    int eA = __builtin_amdgcn_readfirstlane(rowptr[vA]);
    int mA = __builtin_amdgcn_readfirstlane(rowptr[vA + 1]);
    int eB = mA;
    int mB = __builtin_amdgcn_readfirstlane(rowptr[vB + 1]);
    float accA = 0.0f, accB = 0.0f;
    while (eA + 8 <= mA && eB + 8 <= mB) {
        int2 qA[8], qB[8];
#pragma unroll
        for (int i = 0; i < 8; ++i) { qA[i] = epack[eA + i]; qB[i] = epack[eB + i]; }
        __half gA[8], gB[8];
#pragma unroll
        for (int i = 0; i < 8; ++i) {
            gA[i] = h2s[(size_t)(qA[i].x & 0x1FFFF) * HID + lane];
            gB[i] = h2s[(size_t)(qB[i].x & 0x1FFFF) * HID + lane];
        }
#pragma unroll
        for (int i = 0; i < 8; ++i) {
            accA += __half2float(gA[i]);
            accB += __half2float(gB[i]);
        }
        eA += 8; eB += 8;
    }
    for (; eA + 8 <= mA; eA += 8) {
        int2 q[8];
#pragma unroll
        for (int i = 0; i < 8; ++i) q[i] = epack[eA + i];
        __half g[8];
#pragma unroll
        for (int i = 0; i < 8; ++i) g[i] = h2s[(size_t)(q[i].x & 0x1FFFF) * HID + lane];
#pragma unroll
        for (int i = 0; i < 8; ++i) accA += __half2float(g[i]);
    }
    for (; eA < mA; ++eA) {
        int2 q = epack[eA];
        accA += __half2float(h2s[(size_t)(q.x & 0x1FFFF) * HID + lane]);
    }
    for (; eB + 8 <= mB; eB += 8) {
        int2 q[8];
#pragma unroll
        for (int i = 0; i < 8; ++i) q[i] = epack[eB + i];
        __half g[8];
#pragma unroll
        for (int i = 0; i < 8; ++i) g[i] = h2s[(size_t)(q[i].x & 0x1FFFF) * HID + lane];
#pragma unroll
        for (int i = 0; i < 8; ++i) accB += __half2float(g[i]);
    }
    for (; eB < mB; ++eB) {
        int2 q = epack[eB];
        accB += __half2float(h2s[(size_t)(q.x & 0x1FFFF) * HID + lane]);
    }
    float bv = b2[lane];
    float dvA = dis[vA];
    float selfA = __half2float(h2s[(size_t)vA * HID + lane]);
    float valA = dvA * (accA + selfA) + bv;
    valA = valA > 0.0f ? valA : 0.0f;
    float dvB = dis[vB];
    float selfB = __half2float(h2s[(size_t)vB * HID + lane]);
    float valB = dvB * (accB + selfB) + bv;
    valB = valB > 0.0f ? valB : 0.0f;
    int gA = batch[vA], gB = batch[vB];
    if (gA == gB) {
        unsafeAtomicAdd(&pooled[gA * HID + lane], valA + valB);  // merged: half the atomic lines
    } else {
        unsafeAtomicAdd(&pooled[gA * HID + lane], valA);
        unsafeAtomicAdd(&pooled[gB * HID + lane], valB);
    }
}

// ---------------- logits ----------------
__global__ __launch_bounds__(64) void logits_kernel(
    const float* __restrict__ pooled, const int* __restrict__ cnt,
    const float* __restrict__ Wl, const float* __restrict__ bl,
    float* __restrict__ out) {
    __shared__ float row[HID];
    int g = blockIdx.x, t = threadIdx.x;
    int c = cnt[g]; if (c < 1) c = 1;
    row[t] = pooled[g * HID + t] / (float)c;
    __syncthreads();
    if (t < N_CLASSES) {
        float acc = bl[t];
#pragma unroll
        for (int k = 0; k < HID; ++k) acc = fmaf(row[k], Wl[k * N_CLASSES + t], acc);
        out[g * N_CLASSES + t] = acc;
    }
}

extern "C" void kernel_launch(void* const* d_in, const int* in_sizes, int n_in,
                              void* d_out, int out_size, void* d_ws, size_t ws_size,
                              hipStream_t stream) {
    const int*   shape_id = (const int*)d_in[0];
    const int*   color_id = (const int*)d_in[1];
    const int*   edge_idx = (const int*)d_in[2];
    const int*   batch    = (const int*)d_in[3];
    const float* st       = (const float*)d_in[4];
    const float* ct       = (const float*)d_in[5];
    const float* W1       = (const float*)d_in[6];
    const float* b1       = (const float*)d_in[7];
    const float* W2       = (const float*)d_in[8];
    const float* b2       = (const float*)d_in[9];
    const float* Wl       = (const float*)d_in[10];
    const float* bl       = (const float*)d_in[11];
    float* out = (float*)d_out;

    const int* src = edge_idx;
    const int* dst = edge_idx + N_EDGES;

    // workspace layout
    char* ws = (char*)d_ws;
    int*    combo   = (int*)   (ws + 0);            //   400,384 B
    float*  dis     = (float*) (ws + 400384);       //   400,384 B
    int*    bktbase = (int*)   (ws + 800768);       //     1,024 B
    int*    rowptr  = (int*)   (ws + 1201152);      //   400,384 B
    __half* TCh     = (__half*)(ws + 1603584);      //    19,968 B
    float*  pooled  = (float*) (ws + 1623552);      //   262,144 B
    int*    cnt     = (int*)   (ws + 1885696);      //     4,096 B
    int*    gcur    = (int*)   (ws + 1889792);      //     1,024 B
    int2*   epack   = (int2*)  (ws + 1890816);      // 12,800,000 B
    int2*   gbin    = (int2*)  (ws + 14690816);     // 14,680,064 B
    __half* h2s     = (__half*)(ws + 29370880);     // 12,800,000 B (total ~42.2 MB)

    hipMemsetAsync(pooled, 0, N_GRAPHS * HID * sizeof(float) + N_GRAPHS * sizeof(int), stream);
    hipMemsetAsync(gcur, 0, NBUCK * sizeof(int), stream);

    // 1. per-node combo + per-graph counts
    prep_kernel<<<SCAN_BLOCKS, 256, 0, stream>>>(shape_id, color_id, batch, combo, cnt);

    // 2. combined (shape,color)->h1 table (fp16)
    tc_kernel<<<NCOMBO, 64, 0, stream>>>(st, ct, W1, TCh);

    // 3. bin edges by dst-bucket
    binA_kernel<<<(N_EDGES + EPB - 1) / EPB, 512, 0, stream>>>(src, dst, combo, gcur, gbin);

    // 4. bucket bases from gcur
    bscan_kernel<<<1, 256, 0, stream>>>(gcur, bktbase);

    // 5. per-bucket degrees -> dis + rowptr
    bucket_kernel<<<NBUCK, 512, 0, stream>>>(gbin, gcur, bktbase, dis, rowptr);

    // 6. per-bucket scatter to CSR (1024 thr)
    binB_kernel<<<NBUCK, 1024, 0, stream>>>(gbin, gcur, rowptr, dis, epack);

    // 7. fused layer-1 aggregate + mm2 -> h2s (R16: 2 pairs/wave, grid 6250)
    agg1_mm2_kernel<<<6250, 256, 0, stream>>>(epack, rowptr, combo, dis, TCh, W2, b1, h2s);

    // 8. layer-2 aggregate + pool (paired nodes, merged same-graph atomic)
    agg2_pool_kernel<<<N_NODES / 8, 256, 0, stream>>>(epack, rowptr, h2s, dis, b2,
                                                      batch, pooled);

    // 9. logits
    logits_kernel<<<N_GRAPHS, 64, 0, stream>>>(pooled, cnt, Wl, bl, out);
}